// Round 2
// baseline (1881.106 us; speedup 1.0000x reference)
//
#include <hip/hip_runtime.h>
#include <hip/hip_bf16.h>

typedef __attribute__((ext_vector_type(8))) short bf16x8;
typedef __attribute__((ext_vector_type(4))) float f32x4;

#define HH 96
#define WWD 96
#define CIN 32
#define FF 32
#define TT 12
#define HW (HH*WWD)            // 9216
#define NPOS (8*HW)            // 73728
#define XELEMS (8*TT*HW*CIN)   // 28,311,552
#define HELEMS (NPOS*FF)       // 2,359,296
#define NROWS 768              // one block per (batch,row); 3 blocks/CU, all co-resident

// LDS layout: [slab 0..5][q 0..3][xc 0..97] chunks of 8 bf16 (16B).
// slab 0..2 = x rows ky=0..2, slab 3..5 = h rows. xc = xv+1 (pad at 0 and 97).
#define LSTRIDE (98*8)
#define LIDX(s,q,xc) ((((s)*4+(q))*98 + (xc))*8)

__device__ __forceinline__ __hip_bfloat16 f2bf(float x) { return __float2bfloat16(x); }

// X fp32 -> bf16, 8 elems/thread
__global__ void cvt_x(const float* __restrict__ X, __hip_bfloat16* __restrict__ Xb) {
    int i = (blockIdx.x * 256 + threadIdx.x) * 8;
    float4 a = *(const float4*)(X + i);
    float4 b = *(const float4*)(X + i + 4);
    __hip_bfloat16 r[8] = { f2bf(a.x), f2bf(a.y), f2bf(a.z), f2bf(a.w),
                            f2bf(b.x), f2bf(b.y), f2bf(b.z), f2bf(b.w) };
    *(bf16x8*)(Xb + i) = *(bf16x8*)r;
}

// Combined weights, B-fragment-major:
//   Wt[(((kk*2+kc)*4+q)*128 + co)*8 + j] = W[kk][ci=kc*32+q*8+j][co]
//   kc=0 -> Wx (x path); kc=1 -> Wx+Wh (h path)
//   (conv(h+x,Wx)+conv(h,Wh) == conv(x,Wx)+conv(h,Wx+Wh))
// Also zeroes the row-ready flags (9216 u32) for this launch.
__global__ void prep_weights(const float* __restrict__ Wx,
                             const float* __restrict__ Wh,
                             __hip_bfloat16* __restrict__ Wt,
                             unsigned int* __restrict__ flags) {
    int idx = blockIdx.x * 256 + threadIdx.x;   // < 73728
    if (blockIdx.x < 36) flags[idx] = 0u;       // 36*256 = 9216 = 12*768
    int j  = idx & 7;
    int co = (idx >> 3) & 127;
    int q  = (idx >> 10) & 3;
    int kc = (idx >> 12) & 1;
    int kk = idx >> 13;
    int wi = (kk * 32 + q * 8 + j) * 128 + co;
    float v = Wx[wi];
    if (kc) v += Wh[wi];
    Wt[idx] = f2bf(v);
}

// Persistent ConvLSTM: one plain-launched kernel runs all 12 steps.
// Co-residency of all 768 blocks is guaranteed by __launch_bounds__(256,3):
// 3 blocks/CU x 256 CU = 768 (LDS 3x37632B = 110KB < 160KB). No grid.sync()
// is used; the only cross-block dependency (h halo rows y+-1 at t-1) is
// enforced by per-row flags with agent-scope release/acquire (release writes
// back L2, acquire invalidates stale L1/L2 per the gfx95x memory model).
// Double-buffered h makes the 2-flag wait WAR-safe: buf[t&1] row y is only
// overwritten at step t+1, which is gated on neighbors' flag t, set only
// after their reads of that slot completed.
__global__ __launch_bounds__(256, 3) void lstm_all(
    const __hip_bfloat16* __restrict__ Xb,    // (8,12,96,96,32) bf16
    const __hip_bfloat16* __restrict__ Wt,    // (9,2,4,128,8) frag-major
    const float* __restrict__ bias,           // (128) fp32
    __hip_bfloat16* __restrict__ hA,          // (8,96,96,32) bf16 h buffer
    __hip_bfloat16* __restrict__ hB,          // (8,96,96,32) bf16 h buffer
    float* __restrict__ Out,                  // (8,12,1,96,96,32) fp32
    unsigned int* __restrict__ flags)         // (12,768) row-ready
{
    __shared__ __align__(16) ushort lds[6 * 4 * 98 * 8];   // 37632 B

    const int tid  = threadIdx.x;
    const int lane = tid & 63;
    const int wave = tid >> 6;     // 0..3
    const int wm   = wave >> 1;    // x-half (48 cols)
    const int wn   = wave & 1;     // f-half (16 channels)
    const int col  = lane & 15;
    const int q    = lane >> 4;

    // XCD swizzle: consecutive hardware blocks -> same batch on one XCD
    // (perf heuristic only; correctness is fence-based)
    const int rid = (blockIdx.x & 7) * 96 + (blockIdx.x >> 3);
    const int bb  = rid / HH;      // batch
    const int yy  = rid % HH;      // image row

    const int f = wn * 16 + col;
    const int prow = bb * HW + yy * WWD;

    // ---- zero the x-halo pad chunks once (never overwritten by staging)
    if (tid < 48) {
        int s = tid >> 3, rem = tid & 7, qq = rem >> 1, e = rem & 1;
        bf16x8 z = {0,0,0,0,0,0,0,0};
        *(bf16x8*)&lds[LIDX(s, qq, e * 97)] = z;
    }

    const float bi  = bias[f];
    const float bfg = bias[32 + f];
    const float bc  = bias[64 + f];
    const float bo  = bias[96 + f];
    const __hip_bfloat16* wbase = Wt + q * 1024 + f * 8;

    float creg[3][4] = {};   // cell state, register-resident across all steps

#pragma unroll 1
    for (int t = 0; t < TT; ++t) {
        const __hip_bfloat16* hin  = (t & 1) ? hB : hA;
        __hip_bfloat16*       hout = (t & 1) ? hA : hB;
        const __hip_bfloat16* xslab = Xb + (size_t)(bb * TT + t) * HW * CIN;
        const __hip_bfloat16* hslab = hin + (size_t)bb * HW * CIN;

        // ---- wait for neighbor rows' h_{t-1} (agent-scope acquire)
        if (t > 0 && tid == 0) {
            const unsigned int* fl = flags + (t - 1) * NROWS;
            if (yy > 0)
                while (__hip_atomic_load(&fl[rid - 1], __ATOMIC_ACQUIRE,
                                         __HIP_MEMORY_SCOPE_AGENT) == 0u)
                    __builtin_amdgcn_s_sleep(1);
            if (yy < HH - 1)
                while (__hip_atomic_load(&fl[rid + 1], __ATOMIC_ACQUIRE,
                                         __HIP_MEMORY_SCOPE_AGENT) == 0u)
                    __builtin_amdgcn_s_sleep(1);
        }
        __syncthreads();   // publish acquire to block; LDS WAR vs prev step

        // ---- stage 6 slabs (3 x-rows, 3 h-rows), 384 16B-chunks each,
        //      transposing [xv][q] (global) -> [q][xv] (LDS)
#pragma unroll
        for (int it = 0; it < 9; ++it) {
            int c = it * 256 + tid;            // < 2304
            int s = c / 384, i = c % 384;
            int xv = i >> 2, qq = i & 3;
            int ky = (s >= 3) ? s - 3 : s;
            int yv = yy + ky - 1;
            bool isH = (s >= 3);
            if ((unsigned)yv < (unsigned)HH && !(isH && t == 0)) {
                const __hip_bfloat16* src = isH ? hslab : xslab;
                bf16x8 v = *(const bf16x8*)(src + (size_t)yv * (WWD * CIN) + xv * CIN + qq * 8);
                *(bf16x8*)&lds[LIDX(s, qq, xv + 1)] = v;
            }
        }
        __syncthreads();

        f32x4 acc[3][4] = {};   // [mt][gate], D: col=lane&15, row=q*4+reg

        for (int kk = 0; kk < 9; ++kk) {
            const int ky = kk / 3, kx = kk % 3;
            const int yv = yy + ky - 1;
            if ((unsigned)yv >= (unsigned)HH) continue;   // block-uniform skip

            bf16x8 ax[3], ah[3];
#pragma unroll
            for (int mt = 0; mt < 3; ++mt) {
                int xc = wm * 48 + mt * 16 + col + kx;    // xv+1, in [0,97]
                ax[mt] = *(const bf16x8*)&lds[LIDX(ky, q, xc)];
                if (t > 0)
                    ah[mt] = *(const bf16x8*)&lds[LIDX(3 + ky, q, xc)];
            }

#pragma unroll
            for (int kc = 0; kc < 2; ++kc) {
                if (kc == 1 && t == 0) break;   // h==0 at step 0
                const __hip_bfloat16* bb8 = wbase + (kk * 2 + kc) * 4096;
                bf16x8 bf[4];
#pragma unroll
                for (int nt = 0; nt < 4; ++nt)
                    bf[nt] = *(const bf16x8*)(bb8 + nt * 256);
#pragma unroll
                for (int mt = 0; mt < 3; ++mt) {
                    bf16x8 a = (kc == 0) ? ax[mt] : ah[mt];
#pragma unroll
                    for (int nt = 0; nt < 4; ++nt) {
                        acc[mt][nt] = __builtin_amdgcn_mfma_f32_16x16x32_bf16(
                            a, bf[nt], acc[mt][nt], 0, 0, 0);
                    }
                }
            }
        }

        // ---- fused gate epilogue (Keras i,f,c,o; hard_sigmoid gates)
        float* orow = Out + ((size_t)(bb * TT + t) * HW + yy * WWD) * FF;
        __hip_bfloat16* hwrow = hout + (size_t)prow * CIN;

#pragma unroll
        for (int mt = 0; mt < 3; ++mt) {
#pragma unroll
            for (int r = 0; r < 4; ++r) {
                int xo = wm * 48 + mt * 16 + q * 4 + r;
                float zi = acc[mt][0][r] + bi;
                float zf = acc[mt][1][r] + bfg;
                float zc = acc[mt][2][r] + bc;
                float zo = acc[mt][3][r] + bo;
                float ig = fminf(fmaxf(0.2f * zi + 0.5f, 0.f), 1.f);
                float fg = fminf(fmaxf(0.2f * zf + 0.5f, 0.f), 1.f);
                float og = fminf(fmaxf(0.2f * zo + 0.5f, 0.f), 1.f);
                float g  = tanhf(zc);
                float cn = fg * creg[mt][r] + ig * g;
                creg[mt][r] = cn;
                float h = og * tanhf(cn);
                hwrow[xo * CIN + f] = f2bf(h);
                orow[xo * FF + f] = h;
            }
        }

        // ---- publish h_t: drain block stores, device-scope release, set flag
        if (t < TT - 1) {
            __syncthreads();   // compiler emits vmcnt(0) drain before barrier
            if (tid == 0) {
                __threadfence();   // agent-scope: write back L2 so halo is visible
                __hip_atomic_store(&flags[t * NROWS + rid], 1u,
                                   __ATOMIC_RELEASE, __HIP_MEMORY_SCOPE_AGENT);
            }
        }
    }
}

extern "C" void kernel_launch(void* const* d_in, const int* in_sizes, int n_in,
                              void* d_out, int out_size, void* d_ws, size_t ws_size,
                              hipStream_t stream) {
    const float* X    = (const float*)d_in[0];
    const float* Wx   = (const float*)d_in[1];
    const float* Wh   = (const float*)d_in[2];
    const float* bias = (const float*)d_in[3];
    float* Out = (float*)d_out;

    // ws: Wt bf16 | Xb bf16 | hA bf16 | hB bf16 | flags u32
    char* w = (char*)d_ws;
    __hip_bfloat16* Wt = (__hip_bfloat16*)w;   w += 9 * 2 * 4 * 128 * 8 * 2;
    __hip_bfloat16* Xb = (__hip_bfloat16*)w;   w += (size_t)XELEMS * 2;
    __hip_bfloat16* hA = (__hip_bfloat16*)w;   w += (size_t)HELEMS * 2;
    __hip_bfloat16* hB = (__hip_bfloat16*)w;   w += (size_t)HELEMS * 2;
    unsigned int* flags = (unsigned int*)w;    // 12*768 u32 = 36 KB

    cvt_x<<<XELEMS / (256 * 8), 256, 0, stream>>>(X, Xb);
    prep_weights<<<288, 256, 0, stream>>>(Wx, Wh, Wt, flags);
    lstm_all<<<NROWS, 256, 0, stream>>>(Xb, Wt, bias, hA, hB, Out, flags);
}

// Round 4
// 1161.423 us; speedup vs baseline: 1.6197x; 1.6197x over previous
//
#include <hip/hip_runtime.h>
#include <hip/hip_bf16.h>

typedef __attribute__((ext_vector_type(8))) short bf16x8;
typedef __attribute__((ext_vector_type(4))) float f32x4;

#define HH 96
#define WWD 96
#define CIN 32
#define FF 32
#define TT 12
#define HW (HH*WWD)            // 9216
#define NPOS (8*HW)            // 73728
#define XELEMS (8*TT*HW*CIN)   // 28,311,552
#define HELEMS (NPOS*FF)       // 2,359,296
#define NROWS 768              // one block per (batch,row); 3 blocks/CU, all co-resident

// LDS layout: [slab 0..5][q 0..3][xc 0..97] chunks of 8 bf16 (16B).
// slab 0..2 = x rows ky=0..2, slab 3..5 = h rows. xc = xv+1 (pad at 0 and 97).
#define LIDX(s,q,xc) ((((s)*4+(q))*98 + (xc))*8)

__device__ __forceinline__ __hip_bfloat16 f2bf(float x) { return __float2bfloat16(x); }

// ---- IC-coherence-point ops. Stores/polls are inline asm with sc0 sc1
// (write-through / bypass to Infinity Cache). NO wholesale cache
// invalidation anywhere. Loads whose results feed compiler code use
// __hip_atomic_load (compiler-managed waitcnt bookkeeping).
__device__ __forceinline__ unsigned ld_flag(const unsigned* p) {
    unsigned v;
    asm volatile("global_load_dword %0, %1, off sc0 sc1\n\ts_waitcnt vmcnt(0)"
                 : "=v"(v) : "v"(p) : "memory");
    return v;
}
__device__ __forceinline__ void st_flag(unsigned* p, unsigned v) {
    asm volatile("global_store_dword %0, %1, off sc0 sc1"
                 :: "v"(p), "v"(v) : "memory");
}
__device__ __forceinline__ void st_h16(__hip_bfloat16* p, unsigned bits) {
    asm volatile("global_store_short %0, %1, off sc0 sc1"
                 :: "v"(p), "v"(bits) : "memory");
}

// X fp32 -> bf16, 8 elems/thread
__global__ void cvt_x(const float* __restrict__ X, __hip_bfloat16* __restrict__ Xb) {
    int i = (blockIdx.x * 256 + threadIdx.x) * 8;
    float4 a = *(const float4*)(X + i);
    float4 b = *(const float4*)(X + i + 4);
    __hip_bfloat16 r[8] = { f2bf(a.x), f2bf(a.y), f2bf(a.z), f2bf(a.w),
                            f2bf(b.x), f2bf(b.y), f2bf(b.z), f2bf(b.w) };
    *(bf16x8*)(Xb + i) = *(bf16x8*)r;
}

// Combined weights, B-fragment-major (see round-0 notes). Also zeroes the
// row-ready flags; the dispatch-end release (L2 writeback) makes the zeros
// visible to lstm_all's IC-point flag loads.
__global__ void prep_weights(const float* __restrict__ Wx,
                             const float* __restrict__ Wh,
                             __hip_bfloat16* __restrict__ Wt,
                             unsigned int* __restrict__ flags) {
    int idx = blockIdx.x * 256 + threadIdx.x;   // < 73728
    if (blockIdx.x < 36) flags[idx] = 0u;       // 36*256 = 9216 = 12*768
    int j  = idx & 7;
    int co = (idx >> 3) & 127;
    int q  = (idx >> 10) & 3;
    int kc = (idx >> 12) & 1;
    int kk = idx >> 13;
    int wi = (kk * 32 + q * 8 + j) * 128 + co;
    float v = Wx[wi];
    if (kc) v += Wh[wi];
    Wt[idx] = f2bf(v);
}

// Persistent ConvLSTM: one kernel, all 12 steps, cell state in registers.
// Co-residency of all 768 blocks guaranteed by __launch_bounds__(256,3)
// (3 blocks/CU x 256 CU; LDS 3x37632B=110KB<160KB). Cross-block h halo goes
// through the Infinity Cache: h stores write-through (sc0 sc1), h halo loads
// are relaxed agent-scope atomics (IC reads, compiler-managed vmcnt).
// X, Wt, Out use normal cached paths and stay L1/L2-resident.
// Writer order: h stores -> vmcnt(0) -> barrier -> flag store (IC FIFO per
// wave => flag=1 at IC implies h data at IC). Reader: flag spin (asm,
// "memory" clobber) -> barrier -> h loads.
__global__ __launch_bounds__(256, 3) void lstm_all(
    const __hip_bfloat16* __restrict__ Xb,    // (8,12,96,96,32) bf16
    const __hip_bfloat16* __restrict__ Wt,    // (9,2,4,128,8) frag-major
    const float* __restrict__ bias,           // (128) fp32
    __hip_bfloat16* __restrict__ hA,          // (8,96,96,32) bf16 h buffer
    __hip_bfloat16* __restrict__ hB,          // (8,96,96,32) bf16 h buffer
    float* __restrict__ Out,                  // (8,12,1,96,96,32) fp32
    unsigned int* __restrict__ flags)         // (12,768) row-ready
{
    __shared__ __align__(16) ushort lds[6 * 4 * 98 * 8];   // 37632 B

    const int tid  = threadIdx.x;
    const int lane = tid & 63;
    const int wave = tid >> 6;     // 0..3
    const int wm   = wave >> 1;    // x-half (48 cols)
    const int wn   = wave & 1;     // f-half (16 channels)
    const int col  = lane & 15;
    const int q    = lane >> 4;

    // XCD swizzle: consecutive hardware blocks -> same batch on one XCD
    // (perf heuristic only; correctness is IC-point-based)
    const int rid = (blockIdx.x & 7) * 96 + (blockIdx.x >> 3);
    const int bb  = rid / HH;      // batch
    const int yy  = rid % HH;      // image row

    const int f = wn * 16 + col;
    const int prow = bb * HW + yy * WWD;

    // ---- zero the x/h halo pad chunks once (never overwritten by staging)
    if (tid < 48) {
        int s = tid >> 3, rem = tid & 7, qq = rem >> 1, e = rem & 1;
        bf16x8 z = {0,0,0,0,0,0,0,0};
        *(bf16x8*)&lds[LIDX(s, qq, e * 97)] = z;
    }

    const float bi  = bias[f];
    const float bfg = bias[32 + f];
    const float bc  = bias[64 + f];
    const float bo  = bias[96 + f];
    const __hip_bfloat16* wbase = Wt + q * 1024 + f * 8;

    float creg[3][4] = {};   // cell state, register-resident across all steps

#pragma unroll 1
    for (int t = 0; t < TT; ++t) {
        const __hip_bfloat16* hin  = (t & 1) ? hB : hA;
        __hip_bfloat16*       hout = (t & 1) ? hA : hB;
        const __hip_bfloat16* xslab = Xb + (size_t)(bb * TT + t) * HW * CIN;
        const __hip_bfloat16* hslab = hin + (size_t)bb * HW * CIN;

        // ---- wait for neighbor rows' h_{t-1}: two parallel spinners
        // (plain IC reads per poll; no cache invalidation)
        if (t > 0) {
            const unsigned* fl = flags + (t - 1) * NROWS;
            if (tid == 0 && yy > 0)
                while (ld_flag(&fl[rid - 1]) == 0u) __builtin_amdgcn_s_sleep(1);
            if (tid == 64 && yy < HH - 1)
                while (ld_flag(&fl[rid + 1]) == 0u) __builtin_amdgcn_s_sleep(1);
        }
        __syncthreads();   // gate staging on spinners; LDS WAR vs prev step

        // ---- stage x slabs (normal cached loads): 1152 16B-chunks
        //      c: s=c/384 slab(0..2), i=c%384, xv=i>>2, qq=i&3
#pragma unroll
        for (int it = 0; it < 5; ++it) {
            int c = it * 256 + tid;
            if (it == 4 && tid >= 128) break;   // c < 1152
            int s = c / 384, i = c % 384;
            int xv = i >> 2, qq = i & 3;
            int yv = yy + s - 1;
            if ((unsigned)yv < (unsigned)HH) {
                bf16x8 v = *(const bf16x8*)(xslab + (size_t)yv * (WWD * CIN) + xv * CIN + qq * 8);
                *(bf16x8*)&lds[LIDX(s, qq, xv + 1)] = v;
            }
        }

        // ---- stage h slabs as 2304 8B-halves via relaxed agent-scope
        //      atomic loads (IC reads, compiler-managed waitcnt)
        if (t > 0) {
#pragma unroll
            for (int it = 0; it < 9; ++it) {
                int c2 = it * 256 + tid;          // < 2304
                int chunk = c2 >> 1, half = c2 & 1;
                int s3 = chunk / 384, i = chunk % 384;
                int xv = i >> 2, qq = i & 3;
                int yv = yy + s3 - 1;
                if ((unsigned)yv < (unsigned)HH) {
                    const unsigned long long* p = (const unsigned long long*)
                        (hslab + (size_t)yv * (WWD * CIN) + xv * CIN + qq * 8 + half * 4);
                    unsigned long long v = __hip_atomic_load(
                        p, __ATOMIC_RELAXED, __HIP_MEMORY_SCOPE_AGENT);
                    *(unsigned long long*)&lds[LIDX(3 + s3, qq, xv + 1) + half * 4] = v;
                }
            }
        }
        __syncthreads();

        f32x4 acc[3][4] = {};   // [mt][gate], D: col=lane&15, row=q*4+reg

        for (int kk = 0; kk < 9; ++kk) {
            const int ky = kk / 3, kx = kk % 3;
            const int yv = yy + ky - 1;
            if ((unsigned)yv >= (unsigned)HH) continue;   // block-uniform skip

            bf16x8 ax[3], ah[3];
#pragma unroll
            for (int mt = 0; mt < 3; ++mt) {
                int xc = wm * 48 + mt * 16 + col + kx;    // xv+1, in [0,97]
                ax[mt] = *(const bf16x8*)&lds[LIDX(ky, q, xc)];
                if (t > 0)
                    ah[mt] = *(const bf16x8*)&lds[LIDX(3 + ky, q, xc)];
            }

#pragma unroll
            for (int kc = 0; kc < 2; ++kc) {
                if (kc == 1 && t == 0) break;   // h==0 at step 0
                const __hip_bfloat16* bb8 = wbase + (kk * 2 + kc) * 4096;
                bf16x8 bf[4];
#pragma unroll
                for (int nt = 0; nt < 4; ++nt)
                    bf[nt] = *(const bf16x8*)(bb8 + nt * 256);
#pragma unroll
                for (int mt = 0; mt < 3; ++mt) {
                    bf16x8 a = (kc == 0) ? ax[mt] : ah[mt];
#pragma unroll
                    for (int nt = 0; nt < 4; ++nt) {
                        acc[mt][nt] = __builtin_amdgcn_mfma_f32_16x16x32_bf16(
                            a, bf[nt], acc[mt][nt], 0, 0, 0);
                    }
                }
            }
        }

        // ---- fused gate epilogue (Keras i,f,c,o; hard_sigmoid gates)
        float* orow = Out + ((size_t)(bb * TT + t) * HW + yy * WWD) * FF;
        __hip_bfloat16* hwrow = hout + (size_t)prow * CIN;
        const bool need_h = (t < TT - 1);

#pragma unroll
        for (int mt = 0; mt < 3; ++mt) {
#pragma unroll
            for (int r = 0; r < 4; ++r) {
                int xo = wm * 48 + mt * 16 + q * 4 + r;
                float zi = acc[mt][0][r] + bi;
                float zf = acc[mt][1][r] + bfg;
                float zc = acc[mt][2][r] + bc;
                float zo = acc[mt][3][r] + bo;
                float ig = fminf(fmaxf(0.2f * zi + 0.5f, 0.f), 1.f);
                float fg = fminf(fmaxf(0.2f * zf + 0.5f, 0.f), 1.f);
                float og = fminf(fmaxf(0.2f * zo + 0.5f, 0.f), 1.f);
                float g  = tanhf(zc);
                float cn = fg * creg[mt][r] + ig * g;
                creg[mt][r] = cn;
                float h = og * tanhf(cn);
                if (need_h) {
                    __hip_bfloat16 hbv = f2bf(h);
                    st_h16(&hwrow[xo * CIN + f],
                           (unsigned)*reinterpret_cast<unsigned short*>(&hbv));
                }
                orow[xo * FF + f] = h;
            }
        }

        // ---- publish h_t: drain write-through stores to IC, block barrier,
        // then one IC-point flag store. No fences, no cache invalidation.
        if (need_h) {
            asm volatile("s_waitcnt vmcnt(0)" ::: "memory");
            __syncthreads();
            if (tid == 0) st_flag(&flags[t * NROWS + rid], 1u);
        }
    }
}

extern "C" void kernel_launch(void* const* d_in, const int* in_sizes, int n_in,
                              void* d_out, int out_size, void* d_ws, size_t ws_size,
                              hipStream_t stream) {
    const float* X    = (const float*)d_in[0];
    const float* Wx   = (const float*)d_in[1];
    const float* Wh   = (const float*)d_in[2];
    const float* bias = (const float*)d_in[3];
    float* Out = (float*)d_out;

    // ws: Wt bf16 | Xb bf16 | hA bf16 | hB bf16 | flags u32
    char* w = (char*)d_ws;
    __hip_bfloat16* Wt = (__hip_bfloat16*)w;   w += 9 * 2 * 4 * 128 * 8 * 2;
    __hip_bfloat16* Xb = (__hip_bfloat16*)w;   w += (size_t)XELEMS * 2;
    __hip_bfloat16* hA = (__hip_bfloat16*)w;   w += (size_t)HELEMS * 2;
    __hip_bfloat16* hB = (__hip_bfloat16*)w;   w += (size_t)HELEMS * 2;
    unsigned int* flags = (unsigned int*)w;    // 12*768 u32 = 36 KB

    cvt_x<<<XELEMS / (256 * 8), 256, 0, stream>>>(X, Xb);
    prep_weights<<<288, 256, 0, stream>>>(Wx, Wh, Wt, flags);
    lstm_all<<<NROWS, 256, 0, stream>>>(Xb, Wt, bias, hA, hB, Out, flags);
}

// Round 6
// 783.466 us; speedup vs baseline: 2.4010x; 1.4824x over previous
//
#include <hip/hip_runtime.h>
#include <hip/hip_bf16.h>

typedef __attribute__((ext_vector_type(8))) short bf16x8;
typedef __attribute__((ext_vector_type(4))) float f32x4;

#define HH 96
#define WWD 96
#define CIN 32
#define FF 32
#define TT 12
#define HW (HH*WWD)            // 9216
#define NPOS (8*HW)            // 73728
#define XELEMS (8*TT*HW*CIN)   // 28,311,552
#define HELEMS (NPOS*FF)       // 2,359,296
#define NROWS 768              // one block per (batch,row); 3 blocks/CU, all co-resident

// LDS layout: [slab 0..5][q 0..3][xc 0..97] chunks of 8 bf16 (16B).
// slab 0..2 = x rows ky=0..2, slab 3..5 = h rows. xc = xv+1 (pad at 0 and 97).
#define LIDX(s,q,xc) ((((s)*4+(q))*98 + (xc))*8)

__device__ __forceinline__ __hip_bfloat16 f2bf(float x) { return __float2bfloat16(x); }

// ---- flag ops: ALWAYS at the Infinity-Cache point (sc0 sc1), the
// round-4-proven protocol. Flags are never dirty in any L2, so no stale
// whole-line writeback can clobber them (the mixed-mode hazard).
__device__ __forceinline__ unsigned ld_flag_ic(const unsigned* p) {
    unsigned v;
    asm volatile("global_load_dword %0, %1, off sc0 sc1\n\ts_waitcnt vmcnt(0)"
                 : "=v"(v) : "v"(p) : "memory");
    return v;
}
__device__ __forceinline__ void st_flag_ic(unsigned* p, unsigned v) {
    asm volatile("global_store_dword %0, %1, off sc0 sc1"
                 :: "v"(p), "v"(v) : "memory");
}
__device__ __forceinline__ void st_h16_ic(__hip_bfloat16* p, unsigned bits) {
    asm volatile("global_store_short %0, %1, off sc0 sc1"
                 :: "v"(p), "v"(bits) : "memory");
}

// X fp32 -> bf16, 8 elems/thread
__global__ void cvt_x(const float* __restrict__ X, __hip_bfloat16* __restrict__ Xb) {
    int i = (blockIdx.x * 256 + threadIdx.x) * 8;
    float4 a = *(const float4*)(X + i);
    float4 b = *(const float4*)(X + i + 4);
    __hip_bfloat16 r[8] = { f2bf(a.x), f2bf(a.y), f2bf(a.z), f2bf(a.w),
                            f2bf(b.x), f2bf(b.y), f2bf(b.z), f2bf(b.w) };
    *(bf16x8*)(Xb + i) = *(bf16x8*)r;
}

// Combined weights, B-fragment-major (see round-0 notes). Also zeroes the
// row-ready flags (12*768) and the XCD-id map (768); dispatch-end release
// flushes the zeros to memory/IC so lstm_all's IC-point loads see them.
__global__ void prep_weights(const float* __restrict__ Wx,
                             const float* __restrict__ Wh,
                             __hip_bfloat16* __restrict__ Wt,
                             unsigned int* __restrict__ flags) {
    int idx = blockIdx.x * 256 + threadIdx.x;   // < 73728
    if (idx < (TT + 1) * NROWS) flags[idx] = 0u;   // 9984 u32
    int j  = idx & 7;
    int co = (idx >> 3) & 127;
    int q  = (idx >> 10) & 3;
    int kc = (idx >> 12) & 1;
    int kk = idx >> 13;
    int wi = (kk * 32 + q * 8 + j) * 128 + co;
    float v = Wx[wi];
    if (kc) v += Wh[wi];
    Wt[idx] = f2bf(v);
}

// Persistent ConvLSTM: one kernel, all 12 steps, cell state in registers.
// Co-residency of all 768 blocks guaranteed by __launch_bounds__(256,3).
// Flags: always IC-point (sc0 sc1) — proven in round 4.
// h halo data: a runtime prepass publishes each block's XCC_ID and derives,
// per producer row p, mode[p] = 1 iff any consumer of p is on a different
// XCD. mode 0: producer h stores normal cached (dirty in the shared L2),
// consumer h loads sc0 (L1-bypass, L2-served, ZERO EA traffic). mode 1:
// sc0 sc1 both sides (IC point). h rows never share cache lines across
// producers (6144B apart), so per-row modes cannot interact.
// Order: h stores -> vmcnt(0) -> barrier -> IC flag store; consumer:
// IC flag poll -> barrier -> mode-matched h loads.
__global__ __launch_bounds__(256, 3) void lstm_all(
    const __hip_bfloat16* __restrict__ Xb,    // (8,12,96,96,32) bf16
    const __hip_bfloat16* __restrict__ Wt,    // (9,2,4,128,8) frag-major
    const float* __restrict__ bias,           // (128) fp32
    __hip_bfloat16* __restrict__ hA,          // (8,96,96,32) bf16 h buffer
    __hip_bfloat16* __restrict__ hB,          // (8,96,96,32) bf16 h buffer
    float* __restrict__ Out,                  // (8,12,1,96,96,32) fp32
    unsigned int* __restrict__ flags)         // (12,768) row-ready | (768) xcd
{
    __shared__ __align__(16) ushort lds[6 * 4 * 98 * 8];   // 37632 B
    __shared__ int smode[3];   // store-mode of producers rid-1, rid, rid+1

    const int tid  = threadIdx.x;
    const int lane = tid & 63;
    const int wave = tid >> 6;     // 0..3
    const int wm   = wave >> 1;    // x-half (48 cols)
    const int wn   = wave & 1;     // f-half (16 channels)
    const int col  = lane & 15;
    const int q    = lane >> 4;

    // XCD swizzle: consecutive hardware blocks -> same batch on one XCD
    // (perf heuristic; correctness comes from the prepass-derived modes)
    const int rid = (blockIdx.x & 7) * 96 + (blockIdx.x >> 3);
    const int bb  = rid / HH;      // batch
    const int yy  = rid % HH;      // image row

    const int f = wn * 16 + col;
    const int prow = bb * HW + yy * WWD;
    unsigned int* xcdmap = flags + TT * NROWS;

    // ---- zero the x/h halo pad chunks once (never overwritten by staging)
    if (tid < 48) {
        int s = tid >> 3, rem = tid & 7, qq = rem >> 1, e = rem & 1;
        bf16x8 z = {0,0,0,0,0,0,0,0};
        *(bf16x8*)&lds[LIDX(s, qq, e * 97)] = z;
    }

    // ---- prepass: publish XCC_ID (IC point), derive per-producer modes.
    // mode[p] = 1 iff any consumer of p (p's in-batch neighbors) is on a
    // different XCD than p. Consumers of p read with mode[p]; p stores with
    // mode[p] — both sides derive the same mode from the same map.
    if (tid == 0) {
        unsigned my;
        asm volatile("s_getreg_b32 %0, hwreg(HW_REG_XCC_ID)" : "=s"(my));
        st_flag_ic(&xcdmap[rid], my + 1u);
        const int ylo = bb * HH, yhi = ylo + HH - 1;
        unsigned xid[5];
        for (int d = 0; d < 5; ++d) {
            int r = rid - 2 + d;
            unsigned val = 0u;
            if (r >= ylo && r <= yhi) {
                if (d == 2) val = my + 1u;
                else do { val = ld_flag_ic(&xcdmap[r]);
                          if (!val) __builtin_amdgcn_s_sleep(1); } while (val == 0u);
            }
            xid[d] = val;
        }
        auto cr = [](unsigned a, unsigned b) {
            return (a != 0u) && (b != 0u) && (a != b);
        };
        smode[0] = (xid[1] != 0u) && (cr(xid[0], xid[1]) || cr(xid[2], xid[1]));
        smode[1] = (cr(xid[1], xid[2]) || cr(xid[3], xid[2]));
        smode[2] = (xid[3] != 0u) && (cr(xid[2], xid[3]) || cr(xid[4], xid[3]));
    }
    __syncthreads();
    const int up_ic   = smode[0];   // producer rid-1's h mode
    const int self_ic = smode[1];   // our own h store mode
    const int dn_ic   = smode[2];   // producer rid+1's h mode

    const float bi  = bias[f];
    const float bfg = bias[32 + f];
    const float bc  = bias[64 + f];
    const float bo  = bias[96 + f];
    const __hip_bfloat16* wbase = Wt + q * 1024 + f * 8;

    float creg[3][4] = {};   // cell state, register-resident across all steps

#pragma unroll 1
    for (int t = 0; t < TT; ++t) {
        const __hip_bfloat16* hin  = (t & 1) ? hB : hA;
        __hip_bfloat16*       hout = (t & 1) ? hA : hB;
        const __hip_bfloat16* xslab = Xb + (size_t)(bb * TT + t) * HW * CIN;
        const __hip_bfloat16* hslab = hin + (size_t)bb * HW * CIN;

        // ---- wait for neighbor rows' h_{t-1}: two parallel IC-point
        // spinners (no cache invalidation per poll)
        if (t > 0) {
            const unsigned* fl = flags + (t - 1) * NROWS;
            if (tid == 0 && yy > 0)
                while (ld_flag_ic(&fl[rid - 1]) == 0u) __builtin_amdgcn_s_sleep(1);
            if (tid == 64 && yy < HH - 1)
                while (ld_flag_ic(&fl[rid + 1]) == 0u) __builtin_amdgcn_s_sleep(1);
        }
        __syncthreads();   // gate staging on spinners; LDS WAR vs prev step

        // ---- stage x slabs (normal cached loads): 1152 16B-chunks
#pragma unroll
        for (int it = 0; it < 5; ++it) {
            int c = it * 256 + tid;
            if (it == 4 && tid >= 128) break;   // c < 1152
            int s = c / 384, i = c % 384;
            int xv = i >> 2, qq = i & 3;
            int yv = yy + s - 1;
            if ((unsigned)yv < (unsigned)HH) {
                bf16x8 v = *(const bf16x8*)(xslab + (size_t)yv * (WWD * CIN) + xv * CIN + qq * 8);
                *(bf16x8*)&lds[LIDX(s, qq, xv + 1)] = v;
            }
        }

        // ---- stage h slabs: per row, 384 16B-chunks, mode-selected cache
        // point. Issue + vmcnt(0) live in ONE asm block so the compiler
        // never touches in-flight destination registers (round-3 lesson).
        if (t > 0) {
#pragma unroll
            for (int s3 = 0; s3 < 3; ++s3) {
                int pm = (s3 == 0) ? up_ic : (s3 == 1) ? self_ic : dn_ic;
                int yv = yy + s3 - 1;
                if ((unsigned)yv >= (unsigned)HH) continue;
                const __hip_bfloat16* rowp = hslab + (size_t)yv * (WWD * CIN);
                int i0 = tid;
                const __hip_bfloat16* p0 = rowp + (i0 >> 2) * CIN + (i0 & 3) * 8;
                int d0 = LIDX(3 + s3, i0 & 3, (i0 >> 2) + 1);
                bf16x8 v0, v1;
                if (tid < 128) {
                    int i1 = 256 + tid;
                    const __hip_bfloat16* p1 = rowp + (i1 >> 2) * CIN + (i1 & 3) * 8;
                    if (pm) asm volatile(
                        "global_load_dwordx4 %0, %2, off sc0 sc1\n\t"
                        "global_load_dwordx4 %1, %3, off sc0 sc1\n\t"
                        "s_waitcnt vmcnt(0)"
                        : "=&v"(v0), "=&v"(v1) : "v"(p0), "v"(p1) : "memory");
                    else asm volatile(
                        "global_load_dwordx4 %0, %2, off sc0\n\t"
                        "global_load_dwordx4 %1, %3, off sc0\n\t"
                        "s_waitcnt vmcnt(0)"
                        : "=&v"(v0), "=&v"(v1) : "v"(p0), "v"(p1) : "memory");
                    *(bf16x8*)&lds[d0] = v0;
                    *(bf16x8*)&lds[LIDX(3 + s3, i1 & 3, (i1 >> 2) + 1)] = v1;
                } else {
                    if (pm) asm volatile(
                        "global_load_dwordx4 %0, %1, off sc0 sc1\n\t"
                        "s_waitcnt vmcnt(0)"
                        : "=&v"(v0) : "v"(p0) : "memory");
                    else asm volatile(
                        "global_load_dwordx4 %0, %1, off sc0\n\t"
                        "s_waitcnt vmcnt(0)"
                        : "=&v"(v0) : "v"(p0) : "memory");
                    *(bf16x8*)&lds[d0] = v0;
                }
            }
        }
        __syncthreads();

        f32x4 acc[3][4] = {};   // [mt][gate], D: col=lane&15, row=q*4+reg

        for (int kk = 0; kk < 9; ++kk) {
            const int ky = kk / 3, kx = kk % 3;
            const int yv = yy + ky - 1;
            if ((unsigned)yv >= (unsigned)HH) continue;   // block-uniform skip

            bf16x8 ax[3], ah[3];
#pragma unroll
            for (int mt = 0; mt < 3; ++mt) {
                int xc = wm * 48 + mt * 16 + col + kx;    // xv+1, in [0,97]
                ax[mt] = *(const bf16x8*)&lds[LIDX(ky, q, xc)];
                if (t > 0)
                    ah[mt] = *(const bf16x8*)&lds[LIDX(3 + ky, q, xc)];
            }

#pragma unroll
            for (int kc = 0; kc < 2; ++kc) {
                if (kc == 1 && t == 0) break;   // h==0 at step 0
                const __hip_bfloat16* bb8 = wbase + (kk * 2 + kc) * 4096;
                bf16x8 bf[4];
#pragma unroll
                for (int nt = 0; nt < 4; ++nt)
                    bf[nt] = *(const bf16x8*)(bb8 + nt * 256);
#pragma unroll
                for (int mt = 0; mt < 3; ++mt) {
                    bf16x8 a = (kc == 0) ? ax[mt] : ah[mt];
#pragma unroll
                    for (int nt = 0; nt < 4; ++nt) {
                        acc[mt][nt] = __builtin_amdgcn_mfma_f32_16x16x32_bf16(
                            a, bf[nt], acc[mt][nt], 0, 0, 0);
                    }
                }
            }
        }

        // ---- fused gate epilogue (Keras i,f,c,o; hard_sigmoid gates)
        float* orow = Out + ((size_t)(bb * TT + t) * HW + yy * WWD) * FF;
        __hip_bfloat16* hwrow = hout + (size_t)prow * CIN;
        const bool need_h = (t < TT - 1);
        float hv[3][4];

#pragma unroll
        for (int mt = 0; mt < 3; ++mt) {
#pragma unroll
            for (int r = 0; r < 4; ++r) {
                int xo = wm * 48 + mt * 16 + q * 4 + r;
                float zi = acc[mt][0][r] + bi;
                float zf = acc[mt][1][r] + bfg;
                float zc = acc[mt][2][r] + bc;
                float zo = acc[mt][3][r] + bo;
                float ig = fminf(fmaxf(0.2f * zi + 0.5f, 0.f), 1.f);
                float fg = fminf(fmaxf(0.2f * zf + 0.5f, 0.f), 1.f);
                float og = fminf(fmaxf(0.2f * zo + 0.5f, 0.f), 1.f);
                float g  = tanhf(zc);
                float cn = fg * creg[mt][r] + ig * g;
                creg[mt][r] = cn;
                float h = og * tanhf(cn);
                hv[mt][r] = h;
                orow[xo * FF + f] = h;
            }
        }

        if (need_h) {
            if (self_ic) {   // cross-XCD consumers: write-through to IC
#pragma unroll
                for (int mt = 0; mt < 3; ++mt)
#pragma unroll
                    for (int r = 0; r < 4; ++r) {
                        int xo = wm * 48 + mt * 16 + q * 4 + r;
                        __hip_bfloat16 hbv = f2bf(hv[mt][r]);
                        st_h16_ic(&hwrow[xo * CIN + f],
                                  (unsigned)*reinterpret_cast<unsigned short*>(&hbv));
                    }
            } else {         // same-XCD consumers: normal cached stores (L2)
#pragma unroll
                for (int mt = 0; mt < 3; ++mt)
#pragma unroll
                    for (int r = 0; r < 4; ++r) {
                        int xo = wm * 48 + mt * 16 + q * 4 + r;
                        hwrow[xo * CIN + f] = f2bf(hv[mt][r]);
                    }
            }
            // publish h_t: drain h stores to their cache point, barrier,
            // then one IC-point flag store.
            asm volatile("s_waitcnt vmcnt(0)" ::: "memory");
            __syncthreads();
            if (tid == 0) st_flag_ic(&flags[t * NROWS + rid], 1u);
        }
    }
}

extern "C" void kernel_launch(void* const* d_in, const int* in_sizes, int n_in,
                              void* d_out, int out_size, void* d_ws, size_t ws_size,
                              hipStream_t stream) {
    const float* X    = (const float*)d_in[0];
    const float* Wx   = (const float*)d_in[1];
    const float* Wh   = (const float*)d_in[2];
    const float* bias = (const float*)d_in[3];
    float* Out = (float*)d_out;

    // ws: Wt bf16 | Xb bf16 | hA bf16 | hB bf16 | flags u32 (12*768 + 768)
    char* w = (char*)d_ws;
    __hip_bfloat16* Wt = (__hip_bfloat16*)w;   w += 9 * 2 * 4 * 128 * 8 * 2;
    __hip_bfloat16* Xb = (__hip_bfloat16*)w;   w += (size_t)XELEMS * 2;
    __hip_bfloat16* hA = (__hip_bfloat16*)w;   w += (size_t)HELEMS * 2;
    __hip_bfloat16* hB = (__hip_bfloat16*)w;   w += (size_t)HELEMS * 2;
    unsigned int* flags = (unsigned int*)w;    // (12+1)*768 u32 = 39 KB

    cvt_x<<<XELEMS / (256 * 8), 256, 0, stream>>>(X, Xb);
    prep_weights<<<288, 256, 0, stream>>>(Wx, Wh, Wt, flags);
    lstm_all<<<NROWS, 256, 0, stream>>>(Xb, Wt, bias, hA, hB, Out, flags);
}